// Round 1
// baseline (465.936 us; speedup 1.0000x reference)
//
#include <hip/hip_runtime.h>
#include <hip/hip_bf16.h>
#include <math.h>

#define N_NODES 100000
#define N_EDGES 1600000
#define FEAT 128
#define EMBED 128
#define N_CLASSES 40
#define N_BATCH 1024

// ---------------------------------------------------------------------------
// Kernel 1: CSR row offsets from sorted edge_dst via per-node binary search.
// off[n] = lower_bound(edge_dst, n); off[N] = E.
// ---------------------------------------------------------------------------
__global__ __launch_bounds__(256) void offsets_kernel(
    const int* __restrict__ dst, int* __restrict__ off) {
  int n = blockIdx.x * 256 + threadIdx.x;
  if (n > N_NODES) return;
  int lo = 0, hi = N_EDGES;
  while (lo < hi) {
    int mid = (lo + hi) >> 1;
    if (dst[mid] < n) lo = mid + 1; else hi = mid;
  }
  off[n] = lo;
}

// ---------------------------------------------------------------------------
// Kernel 2: gather + segment mean (GraphSAGE-mean incl. self loop).
// One wave (64 lanes) per node; lane holds 2 columns as float2.
// Edge src indices are fetched 64-at-a-time (coalesced) and broadcast via
// __shfl so the row loads in the inner loop are independent.
// ---------------------------------------------------------------------------
__global__ __launch_bounds__(256) void agg_mean_kernel(
    const float* __restrict__ x, const int* __restrict__ esrc,
    const int* __restrict__ off, float* __restrict__ mean) {
  const int lane = threadIdx.x & 63;
  const int node = (blockIdx.x << 2) + (threadIdx.x >> 6);
  if (node >= N_NODES) return;
  const float2* __restrict__ x2 = (const float2*)x;
  int e0 = off[node];
  const int e1 = off[node + 1];
  const int deg = e1 - e0;
  float2 self = x2[(size_t)node * 64 + lane];
  float ax = self.x, ay = self.y;
  while (e0 < e1) {
    int cnt = e1 - e0;
    if (cnt > 64) cnt = 64;
    int s = (lane < cnt) ? esrc[e0 + lane] : 0;
    for (int j = 0; j < cnt; ++j) {
      int sj = __shfl(s, j);
      float2 v = x2[(size_t)sj * 64 + lane];
      ax += v.x;
      ay += v.y;
    }
    e0 += cnt;
  }
  const float inv = 1.0f / (float)(deg + 1);
  float2 o;
  o.x = ax * inv;
  o.y = ay * inv;
  ((float2*)mean)[(size_t)node * 64 + lane] = o;
}

// ---------------------------------------------------------------------------
// Kernel 3: out = relu(A @ W + bias), A:[N,128], W:[128,128].
// Tile 128 rows x 128 cols, BK=32, 256 threads, 8x8 micro-tile.
// As padded (+1) so reading a column of As is bank-conflict-free.
// ---------------------------------------------------------------------------
__global__ __launch_bounds__(256) void gemm_bias_relu_kernel(
    const float* __restrict__ A, const float* __restrict__ W,
    const float* __restrict__ bias, float* __restrict__ out) {
  __shared__ float As[128][33];
  __shared__ float Ws[32][128];
  const int tid = threadIdx.x;
  const int tx = tid & 15;   // col group (8 cols each)
  const int ty = tid >> 4;   // row group (8 rows each)
  const int block_row = blockIdx.x * 128;

  float acc[8][8];
#pragma unroll
  for (int i = 0; i < 8; ++i)
#pragma unroll
    for (int j = 0; j < 8; ++j) acc[i][j] = 0.0f;

  for (int kc = 0; kc < 128; kc += 32) {
    // stage A tile (128 x 32)
    {
      const int r0 = tid >> 3;        // 0..31
      const int kk = (tid & 7) * 4;   // 0..28
#pragma unroll
      for (int p = 0; p < 4; ++p) {
        int r = p * 32 + r0;
        int gr = block_row + r;
        float4 v = make_float4(0.f, 0.f, 0.f, 0.f);
        if (gr < N_NODES)
          v = *(const float4*)&A[(size_t)gr * 128 + kc + kk];
        As[r][kk + 0] = v.x;
        As[r][kk + 1] = v.y;
        As[r][kk + 2] = v.z;
        As[r][kk + 3] = v.w;
      }
    }
    // stage W tile (32 x 128)
    {
      const int k0 = tid >> 5;        // 0..7
      const int c = (tid & 31) * 4;
#pragma unroll
      for (int p = 0; p < 4; ++p) {
        int k = p * 8 + k0;
        *(float4*)&Ws[k][c] = *(const float4*)&W[(size_t)(kc + k) * 128 + c];
      }
    }
    __syncthreads();
    for (int k = 0; k < 32; ++k) {
      float a[8], b[8];
#pragma unroll
      for (int i = 0; i < 8; ++i) a[i] = As[ty * 8 + i][k];
      float4 b0 = *(const float4*)&Ws[k][tx * 8];
      float4 b1 = *(const float4*)&Ws[k][tx * 8 + 4];
      b[0] = b0.x; b[1] = b0.y; b[2] = b0.z; b[3] = b0.w;
      b[4] = b1.x; b[5] = b1.y; b[6] = b1.z; b[7] = b1.w;
#pragma unroll
      for (int i = 0; i < 8; ++i)
#pragma unroll
        for (int j = 0; j < 8; ++j) acc[i][j] = fmaf(a[i], b[j], acc[i][j]);
    }
    __syncthreads();
  }

  float bv[8];
#pragma unroll
  for (int j = 0; j < 8; ++j) bv[j] = bias[tx * 8 + j];
#pragma unroll
  for (int i = 0; i < 8; ++i) {
    int gr = block_row + ty * 8 + i;
    if (gr >= N_NODES) continue;
    float4 o0, o1;
    o0.x = fmaxf(acc[i][0] + bv[0], 0.f);
    o0.y = fmaxf(acc[i][1] + bv[1], 0.f);
    o0.z = fmaxf(acc[i][2] + bv[2], 0.f);
    o0.w = fmaxf(acc[i][3] + bv[3], 0.f);
    o1.x = fmaxf(acc[i][4] + bv[4], 0.f);
    o1.y = fmaxf(acc[i][5] + bv[5], 0.f);
    o1.z = fmaxf(acc[i][6] + bv[6], 0.f);
    o1.w = fmaxf(acc[i][7] + bv[7], 0.f);
    *(float4*)&out[(size_t)gr * 128 + tx * 8] = o0;
    *(float4*)&out[(size_t)gr * 128 + tx * 8 + 4] = o1;
  }
}

// ---------------------------------------------------------------------------
// Kernel 4: batch gather + logits + log_softmax. One wave per batch row.
// ---------------------------------------------------------------------------
__global__ __launch_bounds__(256) void classifier_kernel(
    const float* __restrict__ h, const int* __restrict__ batch,
    const float* __restrict__ Wl, const float* __restrict__ bl,
    float* __restrict__ out) {
  __shared__ float rows[4][128];
  const int lane = threadIdx.x & 63;
  const int wid = threadIdx.x >> 6;
  const int b = (blockIdx.x << 2) + wid;   // grid is exactly 1024/4
  const int node = batch[b];
  const float2* __restrict__ h2 = (const float2*)h;
  float2 v = h2[(size_t)node * 64 + lane];
  rows[wid][lane * 2] = v.x;
  rows[wid][lane * 2 + 1] = v.y;
  __syncthreads();
  float s = 0.0f;
  const int c = lane;
  if (c < N_CLASSES) {
    s = bl[c];
    for (int k = 0; k < 128; ++k) s = fmaf(rows[wid][k], Wl[k * N_CLASSES + c], s);
  }
  float m = (c < N_CLASSES) ? s : -3.0e38f;
#pragma unroll
  for (int o = 32; o > 0; o >>= 1) m = fmaxf(m, __shfl_xor(m, o));
  float e = (c < N_CLASSES) ? expf(s - m) : 0.0f;
  float tot = e;
#pragma unroll
  for (int o = 32; o > 0; o >>= 1) tot += __shfl_xor(tot, o);
  if (c < N_CLASSES) out[b * N_CLASSES + c] = s - m - logf(tot);
}

// ---------------------------------------------------------------------------
extern "C" void kernel_launch(void* const* d_in, const int* in_sizes, int n_in,
                              void* d_out, int out_size, void* d_ws, size_t ws_size,
                              hipStream_t stream) {
  const float* features = (const float*)d_in[0];
  const int* edge_src   = (const int*)d_in[1];
  const int* edge_dst   = (const int*)d_in[2];
  const int* batch      = (const int*)d_in[3];
  const float* W1       = (const float*)d_in[4];
  const float* b1       = (const float*)d_in[5];
  const float* W2       = (const float*)d_in[6];
  const float* b2       = (const float*)d_in[7];
  const float* Wl       = (const float*)d_in[8];
  const float* bl       = (const float*)d_in[9];
  float* out = (float*)d_out;

  char* ws = (char*)d_ws;
  int* off = (int*)ws;                                    // (N+1) ints
  size_t ofs = (((size_t)(N_NODES + 1) * 4) + 511) & ~(size_t)511;
  float* bufA = (float*)(ws + ofs);                       // [N,128] mean
  float* bufB = bufA + (size_t)N_NODES * 128;             // [N,128] h

  offsets_kernel<<<(N_NODES + 256) / 256, 256, 0, stream>>>(edge_dst, off);

  // conv1
  agg_mean_kernel<<<(N_NODES + 3) / 4, 256, 0, stream>>>(features, edge_src, off, bufA);
  gemm_bias_relu_kernel<<<(N_NODES + 127) / 128, 256, 0, stream>>>(bufA, W1, b1, bufB);
  // conv2
  agg_mean_kernel<<<(N_NODES + 3) / 4, 256, 0, stream>>>(bufB, edge_src, off, bufA);
  gemm_bias_relu_kernel<<<(N_NODES + 127) / 128, 256, 0, stream>>>(bufA, W2, b2, bufB);
  // classifier
  classifier_kernel<<<N_BATCH / 4, 256, 0, stream>>>(bufB, batch, Wl, bl, out);
}

// Round 2
// 443.869 us; speedup vs baseline: 1.0497x; 1.0497x over previous
//
#include <hip/hip_runtime.h>
#include <hip/hip_bf16.h>
#include <math.h>

#define N_NODES 100000
#define N_EDGES 1600000
#define FEAT 128
#define EMBED 128
#define N_CLASSES 40
#define N_BATCH 1024

// ---------------------------------------------------------------------------
// Kernel 1: CSR row offsets from sorted edge_dst via boundary detection.
// Thread per edge: writes off[d] = i for every segment start d in
// (dst[i-1], dst[i]]. Tail thread fills (dst[E-1], N].
// ---------------------------------------------------------------------------
__global__ __launch_bounds__(256) void offsets_kernel(
    const int* __restrict__ dst, int* __restrict__ off) {
  int i = blockIdx.x * 256 + threadIdx.x;
  if (i >= N_EDGES) return;
  int d1 = dst[i];
  int d0 = (i == 0) ? -1 : dst[i - 1];
  for (int d = d0 + 1; d <= d1; ++d) off[d] = i;
  if (i == N_EDGES - 1) {
    for (int d = d1 + 1; d <= N_NODES; ++d) off[d] = N_EDGES;
  }
}

// ---------------------------------------------------------------------------
// Kernel 2: gather + segment mean (GraphSAGE-mean incl. self loop).
// One wave per node. Gather loop unrolled 8-wide so 8 row loads are in
// flight per wave (was 1 -> latency-serialized at ~1200 cyc/edge).
// 4 accumulator pairs shorten the dependent add chains.
// ---------------------------------------------------------------------------
__global__ __launch_bounds__(256) void agg_mean_kernel(
    const float* __restrict__ x, const int* __restrict__ esrc,
    const int* __restrict__ off, float* __restrict__ mean) {
  const int lane = threadIdx.x & 63;
  const int node = (blockIdx.x << 2) + (threadIdx.x >> 6);
  if (node >= N_NODES) return;
  const float2* __restrict__ x2 = (const float2*)x;
  int e0 = off[node];
  const int e1 = off[node + 1];
  const int deg = e1 - e0;
  float2 self = x2[(size_t)node * 64 + lane];
  float ax0 = self.x, ay0 = self.y;
  float ax1 = 0.f, ay1 = 0.f;
  float ax2 = 0.f, ay2 = 0.f;
  float ax3 = 0.f, ay3 = 0.f;
  while (e0 < e1) {
    int cnt = e1 - e0;
    if (cnt > 64) cnt = 64;
    int s = (lane < cnt) ? esrc[e0 + lane] : 0;
    int j = 0;
    for (; j + 8 <= cnt; j += 8) {
      int s0 = __shfl(s, j + 0), s1 = __shfl(s, j + 1);
      int s2 = __shfl(s, j + 2), s3 = __shfl(s, j + 3);
      int s4 = __shfl(s, j + 4), s5 = __shfl(s, j + 5);
      int s6 = __shfl(s, j + 6), s7 = __shfl(s, j + 7);
      float2 v0 = x2[(size_t)s0 * 64 + lane];
      float2 v1 = x2[(size_t)s1 * 64 + lane];
      float2 v2 = x2[(size_t)s2 * 64 + lane];
      float2 v3 = x2[(size_t)s3 * 64 + lane];
      float2 v4 = x2[(size_t)s4 * 64 + lane];
      float2 v5 = x2[(size_t)s5 * 64 + lane];
      float2 v6 = x2[(size_t)s6 * 64 + lane];
      float2 v7 = x2[(size_t)s7 * 64 + lane];
      ax0 += v0.x; ay0 += v0.y;
      ax1 += v1.x; ay1 += v1.y;
      ax2 += v2.x; ay2 += v2.y;
      ax3 += v3.x; ay3 += v3.y;
      ax0 += v4.x; ay0 += v4.y;
      ax1 += v5.x; ay1 += v5.y;
      ax2 += v6.x; ay2 += v6.y;
      ax3 += v7.x; ay3 += v7.y;
    }
    for (; j < cnt; ++j) {
      int sj = __shfl(s, j);
      float2 v = x2[(size_t)sj * 64 + lane];
      ax0 += v.x; ay0 += v.y;
    }
    e0 += cnt;
  }
  const float inv = 1.0f / (float)(deg + 1);
  float2 o;
  o.x = (ax0 + ax1 + ax2 + ax3) * inv;
  o.y = (ay0 + ay1 + ay2 + ay3) * inv;
  ((float2*)mean)[(size_t)node * 64 + lane] = o;
}

// ---------------------------------------------------------------------------
// Kernel 3: out = relu(A @ W + bias), A:[N,128], W:[128,128].
// Tile 128x128, BK=32, 256 threads, 8x8 micro-tile.
// A tile stored k-major (Ast[k][r], padded stride 132) so the 8 a-values
// per k are 2 broadcast ds_read_b128 instead of 8 strided ds_read_b32.
// FMA order identical to v1 (bitwise-same output).
// ---------------------------------------------------------------------------
__global__ __launch_bounds__(256) void gemm_bias_relu_kernel(
    const float* __restrict__ A, const float* __restrict__ W,
    const float* __restrict__ bias, float* __restrict__ out) {
  __shared__ float Ast[32][132];
  __shared__ float Ws[32][128];
  const int tid = threadIdx.x;
  const int tx = tid & 15;   // col group (8 cols each)
  const int ty = tid >> 4;   // row group (8 rows each)
  const int block_row = blockIdx.x * 128;

  float acc[8][8];
#pragma unroll
  for (int i = 0; i < 8; ++i)
#pragma unroll
    for (int j = 0; j < 8; ++j) acc[i][j] = 0.0f;

  for (int kc = 0; kc < 128; kc += 32) {
    // stage A tile (k-major)
    {
      const int r0 = tid >> 3;        // 0..31
      const int kk = (tid & 7) * 4;   // 0..28
#pragma unroll
      for (int p = 0; p < 4; ++p) {
        int r = p * 32 + r0;
        int gr = block_row + r;
        float4 v = make_float4(0.f, 0.f, 0.f, 0.f);
        if (gr < N_NODES)
          v = *(const float4*)&A[(size_t)gr * 128 + kc + kk];
        Ast[kk + 0][r] = v.x;
        Ast[kk + 1][r] = v.y;
        Ast[kk + 2][r] = v.z;
        Ast[kk + 3][r] = v.w;
      }
    }
    // stage W tile (32 x 128)
    {
      const int k0 = tid >> 5;        // 0..7
      const int c = (tid & 31) * 4;
#pragma unroll
      for (int p = 0; p < 4; ++p) {
        int k = p * 8 + k0;
        *(float4*)&Ws[k][c] = *(const float4*)&W[(size_t)(kc + k) * 128 + c];
      }
    }
    __syncthreads();
#pragma unroll 8
    for (int k = 0; k < 32; ++k) {
      float4 a0 = *(const float4*)&Ast[k][ty * 8];
      float4 a1 = *(const float4*)&Ast[k][ty * 8 + 4];
      float4 b0 = *(const float4*)&Ws[k][tx * 8];
      float4 b1 = *(const float4*)&Ws[k][tx * 8 + 4];
      float a[8] = {a0.x, a0.y, a0.z, a0.w, a1.x, a1.y, a1.z, a1.w};
      float b[8] = {b0.x, b0.y, b0.z, b0.w, b1.x, b1.y, b1.z, b1.w};
#pragma unroll
      for (int i = 0; i < 8; ++i)
#pragma unroll
        for (int j = 0; j < 8; ++j) acc[i][j] = fmaf(a[i], b[j], acc[i][j]);
    }
    __syncthreads();
  }

  float bv[8];
#pragma unroll
  for (int j = 0; j < 8; ++j) bv[j] = bias[tx * 8 + j];
#pragma unroll
  for (int i = 0; i < 8; ++i) {
    int gr = block_row + ty * 8 + i;
    if (gr >= N_NODES) continue;
    float4 o0, o1;
    o0.x = fmaxf(acc[i][0] + bv[0], 0.f);
    o0.y = fmaxf(acc[i][1] + bv[1], 0.f);
    o0.z = fmaxf(acc[i][2] + bv[2], 0.f);
    o0.w = fmaxf(acc[i][3] + bv[3], 0.f);
    o1.x = fmaxf(acc[i][4] + bv[4], 0.f);
    o1.y = fmaxf(acc[i][5] + bv[5], 0.f);
    o1.z = fmaxf(acc[i][6] + bv[6], 0.f);
    o1.w = fmaxf(acc[i][7] + bv[7], 0.f);
    *(float4*)&out[(size_t)gr * 128 + tx * 8] = o0;
    *(float4*)&out[(size_t)gr * 128 + tx * 8 + 4] = o1;
  }
}

// ---------------------------------------------------------------------------
// Kernel 4: batch gather + logits + log_softmax. One wave per batch row.
// ---------------------------------------------------------------------------
__global__ __launch_bounds__(256) void classifier_kernel(
    const float* __restrict__ h, const int* __restrict__ batch,
    const float* __restrict__ Wl, const float* __restrict__ bl,
    float* __restrict__ out) {
  __shared__ float rows[4][128];
  const int lane = threadIdx.x & 63;
  const int wid = threadIdx.x >> 6;
  const int b = (blockIdx.x << 2) + wid;   // grid is exactly 1024/4
  const int node = batch[b];
  const float2* __restrict__ h2 = (const float2*)h;
  float2 v = h2[(size_t)node * 64 + lane];
  rows[wid][lane * 2] = v.x;
  rows[wid][lane * 2 + 1] = v.y;
  __syncthreads();
  float s = 0.0f;
  const int c = lane;
  if (c < N_CLASSES) {
    s = bl[c];
    for (int k = 0; k < 128; ++k) s = fmaf(rows[wid][k], Wl[k * N_CLASSES + c], s);
  }
  float m = (c < N_CLASSES) ? s : -3.0e38f;
#pragma unroll
  for (int o = 32; o > 0; o >>= 1) m = fmaxf(m, __shfl_xor(m, o));
  float e = (c < N_CLASSES) ? expf(s - m) : 0.0f;
  float tot = e;
#pragma unroll
  for (int o = 32; o > 0; o >>= 1) tot += __shfl_xor(tot, o);
  if (c < N_CLASSES) out[b * N_CLASSES + c] = s - m - logf(tot);
}

// ---------------------------------------------------------------------------
extern "C" void kernel_launch(void* const* d_in, const int* in_sizes, int n_in,
                              void* d_out, int out_size, void* d_ws, size_t ws_size,
                              hipStream_t stream) {
  const float* features = (const float*)d_in[0];
  const int* edge_src   = (const int*)d_in[1];
  const int* edge_dst   = (const int*)d_in[2];
  const int* batch      = (const int*)d_in[3];
  const float* W1       = (const float*)d_in[4];
  const float* b1       = (const float*)d_in[5];
  const float* W2       = (const float*)d_in[6];
  const float* b2       = (const float*)d_in[7];
  const float* Wl       = (const float*)d_in[8];
  const float* bl       = (const float*)d_in[9];
  float* out = (float*)d_out;

  char* ws = (char*)d_ws;
  int* off = (int*)ws;                                    // (N+1) ints
  size_t ofs = (((size_t)(N_NODES + 1) * 4) + 511) & ~(size_t)511;
  float* bufA = (float*)(ws + ofs);                       // [N,128] mean
  float* bufB = bufA + (size_t)N_NODES * 128;             // [N,128] h

  offsets_kernel<<<(N_EDGES + 255) / 256, 256, 0, stream>>>(edge_dst, off);

  // conv1
  agg_mean_kernel<<<(N_NODES + 3) / 4, 256, 0, stream>>>(features, edge_src, off, bufA);
  gemm_bias_relu_kernel<<<(N_NODES + 127) / 128, 256, 0, stream>>>(bufA, W1, b1, bufB);
  // conv2
  agg_mean_kernel<<<(N_NODES + 3) / 4, 256, 0, stream>>>(bufB, edge_src, off, bufA);
  gemm_bias_relu_kernel<<<(N_NODES + 127) / 128, 256, 0, stream>>>(bufA, W2, b2, bufB);
  // classifier
  classifier_kernel<<<N_BATCH / 4, 256, 0, stream>>>(bufB, batch, Wl, bl, out);
}

// Round 3
// 212.440 us; speedup vs baseline: 2.1933x; 2.0894x over previous
//
#include <hip/hip_runtime.h>
#include <hip/hip_bf16.h>
#include <math.h>

#define N_NODES 100000
#define N_EDGES 1600000
#define FEAT 128
#define EMBED 128
#define N_CLASSES 40
#define N_BATCH 1024
#define BM_WORDS 3125   // ceil(100000/32); 3125*32 == 100000 exactly

// ---------------------------------------------------------------------------
// Zero the frontier bitmap + counter (d_ws is poisoned 0xAA before each call).
// ---------------------------------------------------------------------------
__global__ __launch_bounds__(256) void zero_kernel(unsigned* __restrict__ bm,
                                                   int* __restrict__ counter) {
  int i = blockIdx.x * 256 + threadIdx.x;
  if (i < BM_WORDS) bm[i] = 0u;
  if (i == 0) *counter = 0;
}

// ---------------------------------------------------------------------------
// CSR row offsets from sorted edge_dst via boundary detection.
// ---------------------------------------------------------------------------
__global__ __launch_bounds__(256) void offsets_kernel(
    const int* __restrict__ dst, int* __restrict__ off) {
  int i = blockIdx.x * 256 + threadIdx.x;
  if (i >= N_EDGES) return;
  int d1 = dst[i];
  int d0 = (i == 0) ? -1 : dst[i - 1];
  for (int d = d0 + 1; d <= d1; ++d) off[d] = i;
  if (i == N_EDGES - 1) {
    for (int d = d1 + 1; d <= N_NODES; ++d) off[d] = N_EDGES;
  }
}

// ---------------------------------------------------------------------------
// Mark frontier = {batch nodes} U {src of edges whose dst is a batch node}.
// One thread per batch entry; fire-and-forget bitmap atomics.
// ---------------------------------------------------------------------------
__global__ __launch_bounds__(256) void mark_kernel(
    const int* __restrict__ batch, const int* __restrict__ esrc,
    const int* __restrict__ off, unsigned* __restrict__ bm) {
  int t = blockIdx.x * 256 + threadIdx.x;
  if (t >= N_BATCH) return;
  int node = batch[t];
  atomicOr(&bm[node >> 5], 1u << (node & 31));
  int e1 = off[node + 1];
  for (int e = off[node]; e < e1; ++e) {
    int s = esrc[e];
    atomicOr(&bm[s >> 5], 1u << (s & 31));
  }
}

// ---------------------------------------------------------------------------
// Compact bitmap -> node list (order irrelevant; per-wave ballot + atomic).
// ---------------------------------------------------------------------------
__global__ __launch_bounds__(256) void compact_kernel(
    const unsigned* __restrict__ bm, int* __restrict__ nodelist,
    int* __restrict__ counter) {
  int n = blockIdx.x * 256 + threadIdx.x;
  bool pred = (n < N_NODES) && ((bm[n >> 5] >> (n & 31)) & 1u);
  unsigned long long mask = __ballot(pred);
  int lane = threadIdx.x & 63;
  int cnt = __popcll(mask);
  if (cnt == 0) return;
  int base = 0;
  if (lane == 0) base = atomicAdd(counter, cnt);
  base = __shfl(base, 0);
  if (pred) {
    int pos = __popcll(mask & ((1ull << lane) - 1ull));
    nodelist[base + pos] = n;
  }
}

// ---------------------------------------------------------------------------
// Shared gather+mean body: wave computes mean over {self} U neighbors.
// 8-wide unrolled (8 row loads in flight), 4 accumulator pairs.
// Same op order as R2 kernel -> bitwise-identical rows.
// ---------------------------------------------------------------------------
__device__ __forceinline__ float2 gather_mean(
    const float2* __restrict__ x2, const int* __restrict__ esrc,
    int e0, int e1, int lane, float2 self) {
  const int deg = e1 - e0;
  float ax0 = self.x, ay0 = self.y;
  float ax1 = 0.f, ay1 = 0.f;
  float ax2 = 0.f, ay2 = 0.f;
  float ax3 = 0.f, ay3 = 0.f;
  while (e0 < e1) {
    int cnt = e1 - e0;
    if (cnt > 64) cnt = 64;
    int s = (lane < cnt) ? esrc[e0 + lane] : 0;
    int j = 0;
    for (; j + 8 <= cnt; j += 8) {
      int s0 = __shfl(s, j + 0), s1 = __shfl(s, j + 1);
      int s2 = __shfl(s, j + 2), s3 = __shfl(s, j + 3);
      int s4 = __shfl(s, j + 4), s5 = __shfl(s, j + 5);
      int s6 = __shfl(s, j + 6), s7 = __shfl(s, j + 7);
      float2 v0 = x2[(size_t)s0 * 64 + lane];
      float2 v1 = x2[(size_t)s1 * 64 + lane];
      float2 v2 = x2[(size_t)s2 * 64 + lane];
      float2 v3 = x2[(size_t)s3 * 64 + lane];
      float2 v4 = x2[(size_t)s4 * 64 + lane];
      float2 v5 = x2[(size_t)s5 * 64 + lane];
      float2 v6 = x2[(size_t)s6 * 64 + lane];
      float2 v7 = x2[(size_t)s7 * 64 + lane];
      ax0 += v0.x; ay0 += v0.y;
      ax1 += v1.x; ay1 += v1.y;
      ax2 += v2.x; ay2 += v2.y;
      ax3 += v3.x; ay3 += v3.y;
      ax0 += v4.x; ay0 += v4.y;
      ax1 += v5.x; ay1 += v5.y;
      ax2 += v6.x; ay2 += v6.y;
      ax3 += v7.x; ay3 += v7.y;
    }
    for (; j < cnt; ++j) {
      int sj = __shfl(s, j);
      float2 v = x2[(size_t)sj * 64 + lane];
      ax0 += v.x; ay0 += v.y;
    }
    e0 += cnt;
  }
  const float inv = 1.0f / (float)(deg + 1);
  float2 o;
  o.x = (ax0 + ax1 + ax2 + ax3) * inv;
  o.y = (ay0 + ay1 + ay2 + ay3) * inv;
  return o;
}

// ---------------------------------------------------------------------------
// conv1 aggregation restricted to frontier list (scatter rows into buf).
// Grid-stride over list; F read from device counter.
// ---------------------------------------------------------------------------
__global__ __launch_bounds__(256) void agg_frontier_kernel(
    const float* __restrict__ x, const int* __restrict__ esrc,
    const int* __restrict__ off, const int* __restrict__ nodelist,
    const int* __restrict__ fcount, float* __restrict__ meanout) {
  const int lane = threadIdx.x & 63;
  const int wid = threadIdx.x >> 6;
  const int F = *fcount;
  const float2* __restrict__ x2 = (const float2*)x;
  for (int i = (blockIdx.x << 2) + wid; i < F; i += gridDim.x << 2) {
    int node = nodelist[i];
    int e0 = off[node], e1 = off[node + 1];
    float2 self = x2[(size_t)node * 64 + lane];
    float2 o = gather_mean(x2, esrc, e0, e1, lane, self);
    ((float2*)meanout)[(size_t)node * 64 + lane] = o;
  }
}

// ---------------------------------------------------------------------------
// conv2 aggregation over the 1024 batch entries -> compact [1024,128].
// ---------------------------------------------------------------------------
__global__ __launch_bounds__(256) void agg_batch_kernel(
    const float* __restrict__ h1, const int* __restrict__ esrc,
    const int* __restrict__ off, const int* __restrict__ batch,
    float* __restrict__ mean2c) {
  const int lane = threadIdx.x & 63;
  const int b = (blockIdx.x << 2) + (threadIdx.x >> 6);  // grid = 256 exact
  int node = batch[b];
  int e0 = off[node], e1 = off[node + 1];
  const float2* __restrict__ h2p = (const float2*)h1;
  float2 self = h2p[(size_t)node * 64 + lane];
  float2 o = gather_mean(h2p, esrc, e0, e1, lane, self);
  ((float2*)mean2c)[(size_t)b * 64 + lane] = o;
}

// ---------------------------------------------------------------------------
// Row-indirect GEMM: buf[nl[i]] = relu(buf[nl[i]] @ W + bias), in place.
// Tile = 128 list entries x 128 cols, BK=32, 8x8 micro-tile, k-major A tile.
// In-place is safe: each row's output depends only on that row; list entries
// are distinct and partitioned disjointly across tiles.
// ---------------------------------------------------------------------------
__global__ __launch_bounds__(256) void gemm_frontier_kernel(
    float* __restrict__ buf, const float* __restrict__ W,
    const float* __restrict__ bias, const int* __restrict__ nodelist,
    const int* __restrict__ fcount) {
  __shared__ float Ast[32][132];
  __shared__ float Ws[32][128];
  const int tid = threadIdx.x;
  const int tx = tid & 15;
  const int ty = tid >> 4;
  const int F = *fcount;
  const int ntiles = (F + 127) >> 7;

  for (int t = blockIdx.x; t < ntiles; t += gridDim.x) {
    const int base = t << 7;
    float acc[8][8];
#pragma unroll
    for (int i = 0; i < 8; ++i)
#pragma unroll
      for (int j = 0; j < 8; ++j) acc[i][j] = 0.0f;

    // row indices this thread stages (invariant over kc)
    const int r0 = tid >> 3;       // 0..31
    const int kk = (tid & 7) * 4;  // 0..28
    int grow[4];
#pragma unroll
    for (int p = 0; p < 4; ++p) {
      int idx = base + p * 32 + r0;
      grow[p] = (idx < F) ? nodelist[idx] : -1;
    }

    for (int kc = 0; kc < 128; kc += 32) {
#pragma unroll
      for (int p = 0; p < 4; ++p) {
        int r = p * 32 + r0;
        float4 v = make_float4(0.f, 0.f, 0.f, 0.f);
        if (grow[p] >= 0)
          v = *(const float4*)&buf[(size_t)grow[p] * 128 + kc + kk];
        Ast[kk + 0][r] = v.x;
        Ast[kk + 1][r] = v.y;
        Ast[kk + 2][r] = v.z;
        Ast[kk + 3][r] = v.w;
      }
      {
        const int k0 = tid >> 5;
        const int c = (tid & 31) * 4;
#pragma unroll
        for (int p = 0; p < 4; ++p) {
          int k = p * 8 + k0;
          *(float4*)&Ws[k][c] = *(const float4*)&W[(size_t)(kc + k) * 128 + c];
        }
      }
      __syncthreads();
#pragma unroll 8
      for (int k = 0; k < 32; ++k) {
        float4 a0 = *(const float4*)&Ast[k][ty * 8];
        float4 a1 = *(const float4*)&Ast[k][ty * 8 + 4];
        float4 b0 = *(const float4*)&Ws[k][tx * 8];
        float4 b1 = *(const float4*)&Ws[k][tx * 8 + 4];
        float a[8] = {a0.x, a0.y, a0.z, a0.w, a1.x, a1.y, a1.z, a1.w};
        float b[8] = {b0.x, b0.y, b0.z, b0.w, b1.x, b1.y, b1.z, b1.w};
#pragma unroll
        for (int i = 0; i < 8; ++i)
#pragma unroll
          for (int j = 0; j < 8; ++j) acc[i][j] = fmaf(a[i], b[j], acc[i][j]);
      }
      __syncthreads();
    }

    float bv[8];
#pragma unroll
    for (int j = 0; j < 8; ++j) bv[j] = bias[tx * 8 + j];
#pragma unroll
    for (int i = 0; i < 8; ++i) {
      int idx = base + ty * 8 + i;
      if (idx >= F) continue;
      int gr = nodelist[idx];
      float4 o0, o1;
      o0.x = fmaxf(acc[i][0] + bv[0], 0.f);
      o0.y = fmaxf(acc[i][1] + bv[1], 0.f);
      o0.z = fmaxf(acc[i][2] + bv[2], 0.f);
      o0.w = fmaxf(acc[i][3] + bv[3], 0.f);
      o1.x = fmaxf(acc[i][4] + bv[4], 0.f);
      o1.y = fmaxf(acc[i][5] + bv[5], 0.f);
      o1.z = fmaxf(acc[i][6] + bv[6], 0.f);
      o1.w = fmaxf(acc[i][7] + bv[7], 0.f);
      *(float4*)&buf[(size_t)gr * 128 + tx * 8] = o0;
      *(float4*)&buf[(size_t)gr * 128 + tx * 8 + 4] = o1;
    }
  }
}

// ---------------------------------------------------------------------------
// Fused tail: h2 = relu(mean2c @ W2 + b2); logits = h2 @ Wl + bl;
// out = log_softmax(logits). 16 batch rows per block, 64 blocks.
// ---------------------------------------------------------------------------
__global__ __launch_bounds__(256) void tail_kernel(
    const float* __restrict__ mean2c, const float* __restrict__ W2,
    const float* __restrict__ b2, const float* __restrict__ Wl,
    const float* __restrict__ bl, float* __restrict__ out) {
  __shared__ float W2s[128][128];
  __shared__ float Wls[128 * N_CLASSES];
  __shared__ float ms[16][128];
  __shared__ float h2[16][128];
  __shared__ float b2s[128];
  __shared__ float bls[N_CLASSES];
  const int tid = threadIdx.x;
  const int e0 = blockIdx.x * 16;

  for (int i = tid; i < 4096; i += 256)
    ((float4*)W2s)[i] = ((const float4*)W2)[i];
  for (int i = tid; i < (128 * N_CLASSES) / 4; i += 256)
    ((float4*)Wls)[i] = ((const float4*)Wl)[i];
  for (int i = tid; i < 512; i += 256)
    ((float4*)ms)[i] = ((const float4*)(mean2c + (size_t)e0 * 128))[i];
  if (tid < 128) b2s[tid] = b2[tid];
  if (tid < N_CLASSES) bls[tid] = bl[tid];
  __syncthreads();

  // h2 = relu(ms @ W2 + b2): thread -> (row, 8 cols)
  {
    const int row = tid >> 4;
    const int c0 = (tid & 15) * 8;
    float acc[8];
#pragma unroll
    for (int j = 0; j < 8; ++j) acc[j] = 0.f;
    for (int k = 0; k < 128; ++k) {
      float mk = ms[row][k];
      float4 w0 = *(const float4*)&W2s[k][c0];
      float4 w1 = *(const float4*)&W2s[k][c0 + 4];
      acc[0] = fmaf(mk, w0.x, acc[0]);
      acc[1] = fmaf(mk, w0.y, acc[1]);
      acc[2] = fmaf(mk, w0.z, acc[2]);
      acc[3] = fmaf(mk, w0.w, acc[3]);
      acc[4] = fmaf(mk, w1.x, acc[4]);
      acc[5] = fmaf(mk, w1.y, acc[5]);
      acc[6] = fmaf(mk, w1.z, acc[6]);
      acc[7] = fmaf(mk, w1.w, acc[7]);
    }
#pragma unroll
    for (int j = 0; j < 8; ++j)
      h2[row][c0 + j] = fmaxf(acc[j] + b2s[c0 + j], 0.f);
  }
  __syncthreads();

  // logits + log_softmax: wave per 4 rows, lane = class
  {
    const int lane = tid & 63;
    const int wv = tid >> 6;
#pragma unroll
    for (int r4 = 0; r4 < 4; ++r4) {
      const int r = wv * 4 + r4;
      float s = -3.0e38f;
      if (lane < N_CLASSES) {
        s = bls[lane];
        for (int k = 0; k < 128; ++k)
          s = fmaf(h2[r][k], Wls[k * N_CLASSES + lane], s);
      }
      float m = s;
#pragma unroll
      for (int o = 32; o > 0; o >>= 1) m = fmaxf(m, __shfl_xor(m, o));
      float e = (lane < N_CLASSES) ? expf(s - m) : 0.f;
      float tot = e;
#pragma unroll
      for (int o = 32; o > 0; o >>= 1) tot += __shfl_xor(tot, o);
      if (lane < N_CLASSES) out[(size_t)(e0 + r) * N_CLASSES + lane] = s - m - logf(tot);
    }
  }
}

// ---------------------------------------------------------------------------
extern "C" void kernel_launch(void* const* d_in, const int* in_sizes, int n_in,
                              void* d_out, int out_size, void* d_ws, size_t ws_size,
                              hipStream_t stream) {
  const float* features = (const float*)d_in[0];
  const int* edge_src   = (const int*)d_in[1];
  const int* edge_dst   = (const int*)d_in[2];
  const int* batch      = (const int*)d_in[3];
  const float* W1       = (const float*)d_in[4];
  const float* b1       = (const float*)d_in[5];
  const float* W2       = (const float*)d_in[6];
  const float* b2       = (const float*)d_in[7];
  const float* Wl       = (const float*)d_in[8];
  const float* bl       = (const float*)d_in[9];
  float* out = (float*)d_out;

  auto al = [](size_t x) { return (x + 511) & ~(size_t)511; };
  char* p = (char*)d_ws;
  int* off = (int*)p;           p += al((size_t)(N_NODES + 1) * 4);
  unsigned* bm = (unsigned*)p;  p += al((size_t)BM_WORDS * 4);
  int* counter = (int*)p;       p += 512;
  int* nodelist = (int*)p;      p += al((size_t)N_NODES * 4);
  float* buf = (float*)p;       p += (size_t)N_NODES * 128 * 4;   // mean1 -> h1
  float* mean2c = (float*)p;                                      // [1024,128]

  zero_kernel<<<13, 256, 0, stream>>>(bm, counter);
  offsets_kernel<<<(N_EDGES + 255) / 256, 256, 0, stream>>>(edge_dst, off);
  mark_kernel<<<4, 256, 0, stream>>>(batch, edge_src, off, bm);
  compact_kernel<<<(N_NODES + 255) / 256, 256, 0, stream>>>(bm, nodelist, counter);

  // conv1 restricted to frontier
  agg_frontier_kernel<<<2048, 256, 0, stream>>>(features, edge_src, off,
                                                nodelist, counter, buf);
  gemm_frontier_kernel<<<256, 256, 0, stream>>>(buf, W1, b1, nodelist, counter);
  // conv2 restricted to batch
  agg_batch_kernel<<<N_BATCH / 4, 256, 0, stream>>>(buf, edge_src, off, batch, mean2c);
  // h2 + classifier + log_softmax
  tail_kernel<<<N_BATCH / 16, 256, 0, stream>>>(mean2c, W2, b2, Wl, bl, out);
}

// Round 6
// 187.891 us; speedup vs baseline: 2.4798x; 1.1307x over previous
//
#include <hip/hip_runtime.h>
#include <hip/hip_bf16.h>
#include <math.h>

#define N_NODES 100000
#define N_EDGES 1600000
#define FEAT 128
#define EMBED 128
#define N_CLASSES 40
#define N_BATCH 1024
#define LIST_CAP 65536   // expected list length ~17.4K (16.4K edges + 1024)

// ---------------------------------------------------------------------------
// Kernel 1: CSR row offsets from sorted edge_dst (boundary detection) + zero
// the list counter.
// ---------------------------------------------------------------------------
__global__ __launch_bounds__(256) void offsets_kernel(
    const int* __restrict__ dst, int* __restrict__ off,
    int* __restrict__ counter) {
  int i = blockIdx.x * 256 + threadIdx.x;
  if (i == 0) *counter = 0;
  if (i >= N_EDGES) return;
  int d1 = dst[i];
  int d0 = (i == 0) ? -1 : dst[i - 1];
  for (int d = d0 + 1; d <= d1; ++d) off[d] = i;
  if (i == N_EDGES - 1) {
    for (int d = d1 + 1; d <= N_NODES; ++d) off[d] = N_EDGES;
  }
}

// ---------------------------------------------------------------------------
// Kernel 2: build frontier work list (WITH duplicates — benign, see gemm).
// One wave per batch node: append its edge srcs + itself via one wave atomic.
// ---------------------------------------------------------------------------
__global__ __launch_bounds__(256) void build_list_kernel(
    const int* __restrict__ batch, const int* __restrict__ esrc,
    const int* __restrict__ off, int* __restrict__ nodelist,
    int* __restrict__ counter) {
  const int lane = threadIdx.x & 63;
  const int b = (blockIdx.x << 2) + (threadIdx.x >> 6);  // grid = 256 exact
  int node = batch[b];
  int e0 = off[node], e1 = off[node + 1];
  int deg = e1 - e0;
  int base = 0;
  if (lane == 0) base = atomicAdd(counter, deg + 1);
  base = __shfl(base, 0);
  for (int j = lane; j < deg; j += 64)
    if (base + j < LIST_CAP) nodelist[base + j] = esrc[e0 + j];
  if (lane == 0 && base + deg < LIST_CAP) nodelist[base + deg] = node;
}

// ---------------------------------------------------------------------------
// Shared gather+mean body (identical op order to R2/R3 -> bitwise-same rows).
// ---------------------------------------------------------------------------
__device__ __forceinline__ float2 gather_mean(
    const float2* __restrict__ x2, const int* __restrict__ esrc,
    int e0, int e1, int lane, float2 self) {
  const int deg = e1 - e0;
  float ax0 = self.x, ay0 = self.y;
  float ax1 = 0.f, ay1 = 0.f;
  float ax2 = 0.f, ay2 = 0.f;
  float ax3 = 0.f, ay3 = 0.f;
  while (e0 < e1) {
    int cnt = e1 - e0;
    if (cnt > 64) cnt = 64;
    int s = (lane < cnt) ? esrc[e0 + lane] : 0;
    int j = 0;
    for (; j + 8 <= cnt; j += 8) {
      int s0 = __shfl(s, j + 0), s1 = __shfl(s, j + 1);
      int s2 = __shfl(s, j + 2), s3 = __shfl(s, j + 3);
      int s4 = __shfl(s, j + 4), s5 = __shfl(s, j + 5);
      int s6 = __shfl(s, j + 6), s7 = __shfl(s, j + 7);
      float2 v0 = x2[(size_t)s0 * 64 + lane];
      float2 v1 = x2[(size_t)s1 * 64 + lane];
      float2 v2 = x2[(size_t)s2 * 64 + lane];
      float2 v3 = x2[(size_t)s3 * 64 + lane];
      float2 v4 = x2[(size_t)s4 * 64 + lane];
      float2 v5 = x2[(size_t)s5 * 64 + lane];
      float2 v6 = x2[(size_t)s6 * 64 + lane];
      float2 v7 = x2[(size_t)s7 * 64 + lane];
      ax0 += v0.x; ay0 += v0.y;
      ax1 += v1.x; ay1 += v1.y;
      ax2 += v2.x; ay2 += v2.y;
      ax3 += v3.x; ay3 += v3.y;
      ax0 += v4.x; ay0 += v4.y;
      ax1 += v5.x; ay1 += v5.y;
      ax2 += v6.x; ay2 += v6.y;
      ax3 += v7.x; ay3 += v7.y;
    }
    for (; j < cnt; ++j) {
      int sj = __shfl(s, j);
      float2 v = x2[(size_t)sj * 64 + lane];
      ax0 += v.x; ay0 += v.y;
    }
    e0 += cnt;
  }
  const float inv = 1.0f / (float)(deg + 1);
  float2 o;
  o.x = (ax0 + ax1 + ax2 + ax3) * inv;
  o.y = (ay0 + ay1 + ay2 + ay3) * inv;
  return o;
}

// ---------------------------------------------------------------------------
// Kernel 3: conv1 aggregation over the list -> COMPACT meanc[listpos].
// Duplicate list entries recompute identical rows (benign).
// ---------------------------------------------------------------------------
__global__ __launch_bounds__(256) void agg1_kernel(
    const float* __restrict__ x, const int* __restrict__ esrc,
    const int* __restrict__ off, const int* __restrict__ nodelist,
    const int* __restrict__ fcount, float* __restrict__ meanc) {
  const int lane = threadIdx.x & 63;
  const int wid = threadIdx.x >> 6;
  int F = *fcount;
  if (F > LIST_CAP) F = LIST_CAP;
  const float2* __restrict__ x2 = (const float2*)x;
  for (int i = (blockIdx.x << 2) + wid; i < F; i += gridDim.x << 2) {
    int node = nodelist[i];
    int e0 = off[node], e1 = off[node + 1];
    float2 self = x2[(size_t)node * 64 + lane];
    float2 o = gather_mean(x2, esrc, e0, e1, lane, self);
    ((float2*)meanc)[(size_t)i * 64 + lane] = o;
  }
}

// ---------------------------------------------------------------------------
// Kernel 4: h1[nodelist[i]] = relu(meanc[i] @ W1 + b1). A loads coalesced
// (compact), C scattered by node id. Duplicate entries write identical
// bytes to the same row -> benign. Same FMA order as R3 (bitwise-same).
// ---------------------------------------------------------------------------
__global__ __launch_bounds__(256) void gemm1_kernel(
    const float* __restrict__ meanc, const float* __restrict__ W,
    const float* __restrict__ bias, const int* __restrict__ nodelist,
    const int* __restrict__ fcount, float* __restrict__ h1) {
  __shared__ float Ast[32][132];
  __shared__ float Ws[32][128];
  const int tid = threadIdx.x;
  const int tx = tid & 15;
  const int ty = tid >> 4;
  int F = *fcount;
  if (F > LIST_CAP) F = LIST_CAP;
  const int ntiles = (F + 127) >> 7;

  for (int t = blockIdx.x; t < ntiles; t += gridDim.x) {
    const int base = t << 7;
    float acc[8][8];
#pragma unroll
    for (int i = 0; i < 8; ++i)
#pragma unroll
      for (int j = 0; j < 8; ++j) acc[i][j] = 0.0f;

    const int r0 = tid >> 3;       // 0..31
    const int kk = (tid & 7) * 4;  // 0..28

    for (int kc = 0; kc < 128; kc += 32) {
#pragma unroll
      for (int p = 0; p < 4; ++p) {
        int r = p * 32 + r0;
        int lr = base + r;
        float4 v = make_float4(0.f, 0.f, 0.f, 0.f);
        if (lr < F)
          v = *(const float4*)&meanc[(size_t)lr * 128 + kc + kk];
        Ast[kk + 0][r] = v.x;
        Ast[kk + 1][r] = v.y;
        Ast[kk + 2][r] = v.z;
        Ast[kk + 3][r] = v.w;
      }
      {
        const int k0 = tid >> 5;
        const int c = (tid & 31) * 4;
#pragma unroll
        for (int p = 0; p < 4; ++p) {
          int k = p * 8 + k0;
          *(float4*)&Ws[k][c] = *(const float4*)&W[(size_t)(kc + k) * 128 + c];
        }
      }
      __syncthreads();
#pragma unroll 8
      for (int k = 0; k < 32; ++k) {
        float4 a0 = *(const float4*)&Ast[k][ty * 8];
        float4 a1 = *(const float4*)&Ast[k][ty * 8 + 4];
        float4 b0 = *(const float4*)&Ws[k][tx * 8];
        float4 b1 = *(const float4*)&Ws[k][tx * 8 + 4];
        float a[8] = {a0.x, a0.y, a0.z, a0.w, a1.x, a1.y, a1.z, a1.w};
        float b[8] = {b0.x, b0.y, b0.z, b0.w, b1.x, b1.y, b1.z, b1.w};
#pragma unroll
        for (int i = 0; i < 8; ++i)
#pragma unroll
          for (int j = 0; j < 8; ++j) acc[i][j] = fmaf(a[i], b[j], acc[i][j]);
      }
      __syncthreads();
    }

    float bv[8];
#pragma unroll
    for (int j = 0; j < 8; ++j) bv[j] = bias[tx * 8 + j];
#pragma unroll
    for (int i = 0; i < 8; ++i) {
      int idx = base + ty * 8 + i;
      if (idx >= F) continue;
      int gr = nodelist[idx];
      float4 o0, o1;
      o0.x = fmaxf(acc[i][0] + bv[0], 0.f);
      o0.y = fmaxf(acc[i][1] + bv[1], 0.f);
      o0.z = fmaxf(acc[i][2] + bv[2], 0.f);
      o0.w = fmaxf(acc[i][3] + bv[3], 0.f);
      o1.x = fmaxf(acc[i][4] + bv[4], 0.f);
      o1.y = fmaxf(acc[i][5] + bv[5], 0.f);
      o1.z = fmaxf(acc[i][6] + bv[6], 0.f);
      o1.w = fmaxf(acc[i][7] + bv[7], 0.f);
      *(float4*)&h1[(size_t)gr * 128 + tx * 8] = o0;
      *(float4*)&h1[(size_t)gr * 128 + tx * 8 + 4] = o1;
    }
  }
}

// ---------------------------------------------------------------------------
// Kernel 5: fused tail. Per block: 8 batch rows.
//   agg2 (gather h1 + mean) -> ms; h2 = relu(ms @ W2 + b2) (W2 via L2);
//   logits = h2 @ Wl + bl; out = log_softmax.  Static LDS ~29 KB.
// ---------------------------------------------------------------------------
__global__ __launch_bounds__(256) void tail_kernel(
    const float* __restrict__ h1, const int* __restrict__ esrc,
    const int* __restrict__ off, const int* __restrict__ batch,
    const float* __restrict__ W2, const float* __restrict__ b2,
    const float* __restrict__ Wl, const float* __restrict__ bl,
    float* __restrict__ out) {
  __shared__ float Wls[128 * N_CLASSES];
  __shared__ float ms[8][128];
  __shared__ float h2s[8][128];
  const int tid = threadIdx.x;
  const int lane = tid & 63;
  const int wv = tid >> 6;
  const int b0 = blockIdx.x * 8;

  // stage Wl (20 KB)
  for (int i = tid; i < (128 * N_CLASSES) / 4; i += 256)
    ((float4*)Wls)[i] = ((const float4*)Wl)[i];

  // agg2: wave wv handles rows wv and wv+4
  const float2* __restrict__ h1p = (const float2*)h1;
#pragma unroll
  for (int rr = 0; rr < 2; ++rr) {
    int r = wv + rr * 4;
    int node = batch[b0 + r];
    int e0 = off[node], e1 = off[node + 1];
    float2 self = h1p[(size_t)node * 64 + lane];
    float2 o = gather_mean(h1p, esrc, e0, e1, lane, self);
    ms[r][lane * 2] = o.x;
    ms[r][lane * 2 + 1] = o.y;
  }
  __syncthreads();

  // h2 = relu(ms @ W2 + b2): thread -> (row = tid>>5, 4 cols)
  {
    const int row = tid >> 5;
    const int c0 = (tid & 31) * 4;
    float acc[4] = {0.f, 0.f, 0.f, 0.f};
#pragma unroll 4
    for (int k = 0; k < 128; ++k) {
      float mk = ms[row][k];
      float4 w = *(const float4*)&W2[(size_t)k * 128 + c0];
      acc[0] = fmaf(mk, w.x, acc[0]);
      acc[1] = fmaf(mk, w.y, acc[1]);
      acc[2] = fmaf(mk, w.z, acc[2]);
      acc[3] = fmaf(mk, w.w, acc[3]);
    }
#pragma unroll
    for (int j = 0; j < 4; ++j)
      h2s[row][c0 + j] = fmaxf(acc[j] + b2[c0 + j], 0.f);
  }
  __syncthreads();

  // logits + log_softmax: wave wv handles rows 2*wv, 2*wv+1; lane = class
#pragma unroll
  for (int rr = 0; rr < 2; ++rr) {
    const int r = wv * 2 + rr;
    float s = -3.0e38f;
    if (lane < N_CLASSES) {
      s = bl[lane];
      for (int k = 0; k < 128; ++k)
        s = fmaf(h2s[r][k], Wls[k * N_CLASSES + lane], s);
    }
    float m = s;
#pragma unroll
    for (int o = 32; o > 0; o >>= 1) m = fmaxf(m, __shfl_xor(m, o));
    float e = (lane < N_CLASSES) ? expf(s - m) : 0.f;
    float tot = e;
#pragma unroll
    for (int o = 32; o > 0; o >>= 1) tot += __shfl_xor(tot, o);
    if (lane < N_CLASSES)
      out[(size_t)(b0 + r) * N_CLASSES + lane] = s - m - logf(tot);
  }
}

// ---------------------------------------------------------------------------
extern "C" void kernel_launch(void* const* d_in, const int* in_sizes, int n_in,
                              void* d_out, int out_size, void* d_ws, size_t ws_size,
                              hipStream_t stream) {
  const float* features = (const float*)d_in[0];
  const int* edge_src   = (const int*)d_in[1];
  const int* edge_dst   = (const int*)d_in[2];
  const int* batch      = (const int*)d_in[3];
  const float* W1       = (const float*)d_in[4];
  const float* b1       = (const float*)d_in[5];
  const float* W2       = (const float*)d_in[6];
  const float* b2       = (const float*)d_in[7];
  const float* Wl       = (const float*)d_in[8];
  const float* bl       = (const float*)d_in[9];
  float* out = (float*)d_out;

  auto al = [](size_t x) { return (x + 511) & ~(size_t)511; };
  char* p = (char*)d_ws;
  int* off = (int*)p;       p += al((size_t)(N_NODES + 1) * 4);
  int* counter = (int*)p;   p += 512;
  int* nodelist = (int*)p;  p += al((size_t)LIST_CAP * 4);
  float* meanc = (float*)p; p += (size_t)LIST_CAP * 128 * 4;   // [L,128]
  float* h1 = (float*)p;                                       // [N,128]

  offsets_kernel<<<(N_EDGES + 255) / 256, 256, 0, stream>>>(edge_dst, off, counter);
  build_list_kernel<<<N_BATCH / 4, 256, 0, stream>>>(batch, edge_src, off,
                                                     nodelist, counter);
  agg1_kernel<<<2048, 256, 0, stream>>>(features, edge_src, off, nodelist,
                                        counter, meanc);
  gemm1_kernel<<<256, 256, 0, stream>>>(meanc, W1, b1, nodelist, counter, h1);
  tail_kernel<<<N_BATCH / 8, 256, 0, stream>>>(h1, edge_src, off, batch,
                                               W2, b2, Wl, bl, out);
}

// Round 10
// 163.170 us; speedup vs baseline: 2.8555x; 1.1515x over previous
//
#include <hip/hip_runtime.h>
#include <hip/hip_bf16.h>
#include <math.h>

#define N_NODES 100000
#define N_EDGES 1600000
#define FEAT 128
#define EMBED 128
#define N_CLASSES 40
#define N_BATCH 1024

#define RPB 4          // batch rows per block
#define NTHREADS 512   // 8 waves
#define LCAP 512       // local list capacity (mean 68, 4x Poisson(16)+4)
#define CHUNK 128      // GEMM tile rows per pass
#define APAD 132       // LDS leading-dim pad (16B-aligned rows: 132%4==0)

// ---------------------------------------------------------------------------
// Kernel 1: CSR row offsets from sorted edge_dst via boundary detection.
// ---------------------------------------------------------------------------
__global__ __launch_bounds__(256) void offsets_kernel(
    const int* __restrict__ dst, int* __restrict__ off) {
  int i = blockIdx.x * 256 + threadIdx.x;
  if (i >= N_EDGES) return;
  int d1 = dst[i];
  int d0 = (i == 0) ? -1 : dst[i - 1];
  for (int d = d0 + 1; d <= d1; ++d) off[d] = i;
  if (i == N_EDGES - 1) {
    for (int d = d1 + 1; d <= N_NODES; ++d) off[d] = N_EDGES;
  }
}

// ---------------------------------------------------------------------------
// gather+mean body (identical op order to R2..R6 -> bitwise-same rows).
// ---------------------------------------------------------------------------
__device__ __forceinline__ float2 gather_mean(
    const float2* __restrict__ x2, const int* __restrict__ esrc,
    int e0, int e1, int lane, float2 self) {
  const int deg = e1 - e0;
  float ax0 = self.x, ay0 = self.y;
  float ax1 = 0.f, ay1 = 0.f;
  float ax2 = 0.f, ay2 = 0.f;
  float ax3 = 0.f, ay3 = 0.f;
  while (e0 < e1) {
    int cnt = e1 - e0;
    if (cnt > 64) cnt = 64;
    int s = (lane < cnt) ? esrc[e0 + lane] : 0;
    int j = 0;
    for (; j + 8 <= cnt; j += 8) {
      int s0 = __shfl(s, j + 0), s1 = __shfl(s, j + 1);
      int s2 = __shfl(s, j + 2), s3 = __shfl(s, j + 3);
      int s4 = __shfl(s, j + 4), s5 = __shfl(s, j + 5);
      int s6 = __shfl(s, j + 6), s7 = __shfl(s, j + 7);
      float2 v0 = x2[(size_t)s0 * 64 + lane];
      float2 v1 = x2[(size_t)s1 * 64 + lane];
      float2 v2 = x2[(size_t)s2 * 64 + lane];
      float2 v3 = x2[(size_t)s3 * 64 + lane];
      float2 v4 = x2[(size_t)s4 * 64 + lane];
      float2 v5 = x2[(size_t)s5 * 64 + lane];
      float2 v6 = x2[(size_t)s6 * 64 + lane];
      float2 v7 = x2[(size_t)s7 * 64 + lane];
      ax0 += v0.x; ay0 += v0.y;
      ax1 += v1.x; ay1 += v1.y;
      ax2 += v2.x; ay2 += v2.y;
      ax3 += v3.x; ay3 += v3.y;
      ax0 += v4.x; ay0 += v4.y;
      ax1 += v5.x; ay1 += v5.y;
      ax2 += v6.x; ay2 += v6.y;
      ax3 += v7.x; ay3 += v7.y;
    }
    for (; j < cnt; ++j) {
      int sj = __shfl(s, j);
      float2 v = x2[(size_t)sj * 64 + lane];
      ax0 += v.x; ay0 += v.y;
    }
    e0 += cnt;
  }
  const float inv = 1.0f / (float)(deg + 1);
  float2 o;
  o.x = (ax0 + ax1 + ax2 + ax3) * inv;
  o.y = (ay0 + ay1 + ay2 + ay3) * inv;
  return o;
}

// ---------------------------------------------------------------------------
// Mega-kernel: block b fully computes batch rows 4b..4b+3.
//   Phase 0: local list = per-row {edge srcs..., self} (duplicates benign).
//   Phase A: conv1 mean for each list slot -> meanA[k][slot] (LDS, k-major).
//   Phase B: h1 = relu(meanA^T @ W1 + b1) -> overlay LDS [slot][c];
//            deterministic per-segment column sums -> acc2[r][c].
//   Phase C: mean2 = acc2/(deg+1); h2 = relu(mean2 @ W2 + b2);
//            logits = h2 @ Wl + bl; out = log_softmax.
// No cross-block communication; no intermediate global buffers.
// ---------------------------------------------------------------------------
__global__ __launch_bounds__(NTHREADS) void mega_kernel(
    const float* __restrict__ x, const int* __restrict__ esrc,
    const int* __restrict__ off, const int* __restrict__ batch,
    const float* __restrict__ W1, const float* __restrict__ b1,
    const float* __restrict__ W2, const float* __restrict__ b2,
    const float* __restrict__ Wl, const float* __restrict__ bl,
    float* __restrict__ out) {
  __shared__ float meanA[CHUNK][APAD];      // 67.6 KB; overlaid in phase B/C
  __shared__ float acc2[RPB][128];
  __shared__ int list[LCAP];
  __shared__ int segs[RPB], sege[RPB], nodes[RPB], degs[RPB], e0s[RPB];
  __shared__ int Lsh;

  const int tid = threadIdx.x;
  const int lane = tid & 63;
  const int wv = tid >> 6;

  // ---- Phase 0: build local list --------------------------------------
  if (tid < RPB) {
    int node = batch[blockIdx.x * RPB + tid];
    nodes[tid] = node;
    int e0 = off[node], e1 = off[node + 1];
    e0s[tid] = e0;
    degs[tid] = e1 - e0;
  }
  __syncthreads();
  if (tid == 0) {
    int pos = 0;
    for (int r = 0; r < RPB; ++r) {
      segs[r] = pos;
      int d = degs[r];
      if (pos + d + 1 > LCAP) d = LCAP - pos - 1;  // clamp (never in practice)
      pos += d + 1;
      sege[r] = pos;
    }
    Lsh = pos;
  }
  __syncthreads();
  for (int r = 0; r < RPB; ++r) {
    int s0 = segs[r], d = sege[r] - s0 - 1, e0 = e0s[r];
    for (int j = tid; j < d; j += NTHREADS) list[s0 + j] = esrc[e0 + j];
    if (tid == 0) list[sege[r] - 1] = nodes[r];
  }
  for (int i = tid; i < RPB * 128; i += NTHREADS) ((float*)acc2)[i] = 0.f;
  __syncthreads();

  const int L = Lsh;
  const float2* __restrict__ x2 = (const float2*)x;
  float* __restrict__ flat = &meanA[0][0];

  // ---- Phases A+B per chunk -------------------------------------------
  for (int c0 = 0; c0 < L; c0 += CHUNK) {
    const int clen = min(CHUNK, L - c0);

    // Phase A: conv1 means, k-major columns. Wave wv does slots wv,wv+8,...
    for (int sc = wv; sc < clen; sc += 8) {
      int node = list[c0 + sc];
      int e0 = off[node], e1 = off[node + 1];
      float2 self = x2[(size_t)node * 64 + lane];
      float2 o = gather_mean(x2, esrc, e0, e1, lane, self);
      meanA[2 * lane][sc] = o.x;
      meanA[2 * lane + 1][sc] = o.y;
    }
    __syncthreads();

    // Phase B: GEMM (rows=slots, cols=128). thread -> 4 rows x 8 cols.
    const int ty = tid >> 4;   // 0..31 -> rows 4ty..4ty+3
    const int tx = tid & 15;   // cols 8tx..8tx+7
    float accg[4][8];
#pragma unroll
    for (int i = 0; i < 4; ++i)
#pragma unroll
      for (int j = 0; j < 8; ++j) accg[i][j] = 0.f;
#pragma unroll 4
    for (int k = 0; k < 128; ++k) {
      float4 a = *(const float4*)&meanA[k][ty * 4];
      float4 bq0 = *(const float4*)&W1[(size_t)k * 128 + tx * 8];
      float4 bq1 = *(const float4*)&W1[(size_t)k * 128 + tx * 8 + 4];
      float av[4] = {a.x, a.y, a.z, a.w};
      float bv[8] = {bq0.x, bq0.y, bq0.z, bq0.w, bq1.x, bq1.y, bq1.z, bq1.w};
#pragma unroll
      for (int i = 0; i < 4; ++i)
#pragma unroll
        for (int j = 0; j < 8; ++j) accg[i][j] = fmaf(av[i], bv[j], accg[i][j]);
    }
    __syncthreads();   // all meanA reads done before overlay write

    // h1 rows -> overlay flat[s*APAD + c]
    {
      float bb[8];
#pragma unroll
      for (int j = 0; j < 8; ++j) bb[j] = b1[tx * 8 + j];
#pragma unroll
      for (int i = 0; i < 4; ++i) {
        int s = ty * 4 + i;
        if (s < clen) {
          float4 o0, o1;
          o0.x = fmaxf(accg[i][0] + bb[0], 0.f);
          o0.y = fmaxf(accg[i][1] + bb[1], 0.f);
          o0.z = fmaxf(accg[i][2] + bb[2], 0.f);
          o0.w = fmaxf(accg[i][3] + bb[3], 0.f);
          o1.x = fmaxf(accg[i][4] + bb[4], 0.f);
          o1.y = fmaxf(accg[i][5] + bb[5], 0.f);
          o1.z = fmaxf(accg[i][6] + bb[6], 0.f);
          o1.w = fmaxf(accg[i][7] + bb[7], 0.f);
          *(float4*)&flat[s * APAD + tx * 8] = o0;
          *(float4*)&flat[s * APAD + tx * 8 + 4] = o1;
        }
      }
    }
    __syncthreads();

    // Deterministic segment reduction: wave -> (r = wv&3, col half = wv>>2).
    {
      int r = wv & 3;
      int col = ((wv >> 2) << 6) | lane;
      int s0 = max(segs[r] - c0, 0);
      int s1 = min(sege[r] - c0, clen);
      float a = 0.f;
      for (int s = s0; s < s1; ++s) a += flat[s * APAD + col];
      acc2[r][col] += a;
    }
    __syncthreads();
  }

  // ---- Phase C ---------------------------------------------------------
  // mean2 = acc2 / (deg+1)
  if (tid < RPB * 128) {
    int r = tid >> 7;
    acc2[r][tid & 127] *= 1.0f / (float)(degs[r] + 1);
  }
  // stage Wl into overlay (meanA dead now)
  float* Wls = flat;                    // 128*40 floats = 20 KB
  float* h2s = flat + 128 * N_CLASSES;  // RPB*128 floats
  for (int i = tid; i < (128 * N_CLASSES) / 4; i += NTHREADS)
    ((float4*)Wls)[i] = ((const float4*)Wl)[i];
  __syncthreads();

  // h2 = relu(mean2 @ W2 + b2): thread -> (r = tid>>7, c = tid&127)
  {
    const int r = tid >> 7;
    const int c = tid & 127;
    float acc = 0.f;
#pragma unroll 4
    for (int k = 0; k < 128; ++k)
      acc = fmaf(acc2[r][k], W2[(size_t)k * 128 + c], acc);
    h2s[r * 128 + c] = fmaxf(acc + b2[c], 0.f);
  }
  __syncthreads();

  // logits + log_softmax: waves 0..3, wave r; lane = class
  if (wv < RPB) {
    const int r = wv;
    float s = -3.0e38f;
    if (lane < N_CLASSES) {
      s = bl[lane];
      for (int k = 0; k < 128; ++k)
        s = fmaf(h2s[r * 128 + k], Wls[k * N_CLASSES + lane], s);
    }
    float m = s;
#pragma unroll
    for (int o = 32; o > 0; o >>= 1) m = fmaxf(m, __shfl_xor(m, o));
    float e = (lane < N_CLASSES) ? expf(s - m) : 0.f;
    float tot = e;
#pragma unroll
    for (int o = 32; o > 0; o >>= 1) tot += __shfl_xor(tot, o);
    if (lane < N_CLASSES)
      out[(size_t)(blockIdx.x * RPB + r) * N_CLASSES + lane] = s - m - logf(tot);
  }
}

// ---------------------------------------------------------------------------
extern "C" void kernel_launch(void* const* d_in, const int* in_sizes, int n_in,
                              void* d_out, int out_size, void* d_ws, size_t ws_size,
                              hipStream_t stream) {
  const float* features = (const float*)d_in[0];
  const int* edge_src   = (const int*)d_in[1];
  const int* edge_dst   = (const int*)d_in[2];
  const int* batch      = (const int*)d_in[3];
  const float* W1       = (const float*)d_in[4];
  const float* b1       = (const float*)d_in[5];
  const float* W2       = (const float*)d_in[6];
  const float* b2       = (const float*)d_in[7];
  const float* Wl       = (const float*)d_in[8];
  const float* bl       = (const float*)d_in[9];
  float* out = (float*)d_out;

  int* off = (int*)d_ws;  // (N+1) ints

  offsets_kernel<<<(N_EDGES + 255) / 256, 256, 0, stream>>>(edge_dst, off);
  mega_kernel<<<N_BATCH / RPB, NTHREADS, 0, stream>>>(
      features, edge_src, off, batch, W1, b1, W2, b2, Wl, bl, out);
}